// Round 1
// baseline (110.598 us; speedup 1.0000x reference)
//
#include <hip/hip_runtime.h>

#define NN 10000
#define NE 40000

typedef __attribute__((ext_vector_type(8))) short bf16x8;
typedef __attribute__((ext_vector_type(4))) float f32x4;
typedef __attribute__((ext_vector_type(8))) unsigned short u16x8;

__device__ inline unsigned short bf16rne(float f) {
  union { float f; unsigned u; } v; v.f = f;
  return (unsigned short)((v.u + 0x7FFFu + ((v.u >> 16) & 1u)) >> 16);
}

// Reorder ew2 [128 x 2048] f32 -> bf16 MFMA-B fragment order:
// element j of lane l for column-tile ct, k-chunk kk holds
// B[k = kk*32 + (l>>4)*8 + j][c = ct*16 + (l&15)].
// Stored at ushort index ((ct*4+kk)*64 + l)*8 + j  (contiguous 16B per lane).
__global__ void k_reorder(const float* __restrict__ ew2, unsigned short* __restrict__ out) {
  const int l  = threadIdx.x & 63;
  const int kk = threadIdx.x >> 6;   // 4 waves = 4 k-chunks
  const int ct = blockIdx.x;         // 0..127
  const int col = ct * 16 + (l & 15);
  const int g = l >> 4;
  u16x8 v;
#pragma unroll
  for (int j = 0; j < 8; ++j) {
    int k = kk * 32 + g * 8 + j;
    v[j] = bf16rne(ew2[k * 2048 + col]);
  }
  *reinterpret_cast<u16x8*>(out + ((size_t)((ct * 4 + kk) * 64 + l) * 8)) = v;
}

// out[n,KO] = xin[n,KI] @ root[KI,KO] + bias[KO]
template <int KI, int KO>
__global__ void k_root(const float* __restrict__ xin, const float* __restrict__ root,
                       const float* __restrict__ bias, float* __restrict__ out) {
  int idx = blockIdx.x * 256 + threadIdx.x;
  if (idx >= NN * KO) return;
  int n = idx / KO, o = idx % KO;
  float acc = bias[o];
#pragma unroll
  for (int k = 0; k < KI; ++k) acc += xin[n * KI + k] * root[k * KO + o];
  out[idx] = acc;
}

__global__ void k_relu(const float* __restrict__ in, float* __restrict__ out, int n) {
  int idx = blockIdx.x * 256 + threadIdx.x;
  if (idx < n) out[idx] = fmaxf(in[idx], 0.f);
}

// Fused per-edge kernel: H = relu(eattr@ew1+eb1); W = relu(H@ew2+eb2);
// msg[e,o] = sum_i xin[src[e],i] * W[e, i*CO+o]; atomicAdd into aggr[dst[e],o].
// 64 edges per block, 4 waves.
template <int CI, int CO>
__global__ __launch_bounds__(256, 2) void k_edge(
    const int* __restrict__ src, const int* __restrict__ dst,
    const float* __restrict__ eattr,
    const float* __restrict__ ew1, const float* __restrict__ eb1,
    const unsigned short* __restrict__ bfrag, const float* __restrict__ eb2,
    const float* __restrict__ xin, float* __restrict__ aggr) {
  constexpr int TE = 64;
  constexpr int XS = 68;  // padded edge-stride for x-transpose (bank spread, 16B-aligned rows)
  const int tid = threadIdx.x;
  const int e0 = blockIdx.x * TE;

  __shared__ int s_src[TE];
  __shared__ int s_dst[TE];
  __shared__ float s_eattr[TE][16];
  __shared__ float s_ew1[16 * 128];
  __shared__ unsigned short s_hfrag[16 * 64 * 8];  // A-fragment order: [(m*4+kk)*64 + lane][8]
  __shared__ float s_x[CI][XS];                    // transposed gathered source features

  if (tid < TE) { s_src[tid] = src[e0 + tid]; s_dst[tid] = dst[e0 + tid]; }
  for (int i = tid; i < TE * 16; i += 256) s_eattr[i >> 4][i & 15] = eattr[e0 * 16 + i];
  for (int i = tid; i < 16 * 128; i += 256) s_ew1[i] = ew1[i];
  __syncthreads();

  // gather x[src] -> transposed LDS (read coalesced, scatter to [c][e])
  for (int i = tid; i < TE * CI; i += 256) {
    int e = i / CI, c = i % CI;
    s_x[c][e] = xin[(size_t)s_src[e] * CI + c];
  }

  // edge-MLP hidden: H[e][c] = relu(eattr[e]@ew1[:,c] + eb1[c]), stored bf16 in A-frag order
  {
    const int c = tid & 127;
    const int ebase = (tid >> 7) * 32;
    float wcol[16];
#pragma unroll
    for (int k = 0; k < 16; ++k) wcol[k] = s_ew1[k * 128 + c];
    const float b1 = eb1[c];
    const int kk = c >> 5, gg = (c >> 3) & 3, j = c & 7;
    for (int e = ebase; e < ebase + 32; ++e) {
      float acc = b1;
#pragma unroll
      for (int k = 0; k < 16; ++k) acc += s_eattr[e][k] * wcol[k];
      s_hfrag[(((e >> 4) * 4 + kk) * 64 + gg * 16 + (e & 15)) * 8 + j] = bf16rne(fmaxf(acc, 0.f));
    }
  }
  __syncthreads();

  const int l = tid & 63;
  const int w = tid >> 6;
  const int g = l >> 4;
  const int c16 = l & 15;

  // A fragments: 4 M-tiles x 4 K-chunks, loaded once (conflict-free linear b128 reads)
  bf16x8 afrag[4][4];
#pragma unroll
  for (int m = 0; m < 4; ++m)
#pragma unroll
    for (int kk = 0; kk < 4; ++kk)
      afrag[m][kk] = *reinterpret_cast<const bf16x8*>(&s_hfrag[((m * 4 + kk) * 64 + l) * 8]);

  float msg[4][4];
#pragma unroll
  for (int m = 0; m < 4; ++m)
#pragma unroll
    for (int r = 0; r < 4; ++r) msg[m][r] = 0.f;

  const int ocol = (CI == 32) ? (w * 16 + c16) : ((w & 1) * 16 + c16);

  for (int t = 0; t < 32; ++t) {
    // layer1 (CI=32,CO=64): wave w owns o-range w*16, loops all i.
    // layer2 (CI=64,CO=32): wave w owns o-range (w&1)*16, i parity (w>>1).
    const int i  = (CI == 32) ? t : ((w >> 1) + 2 * t);
    const int ct = (CI == 32) ? (t * 4 + w) : (i * 2 + (w & 1));
    const float b = eb2[i * CO + ocol];
    bf16x8 bfr[4];
    const bf16x8* bptr = reinterpret_cast<const bf16x8*>(bfrag) + (size_t)ct * 4 * 64 + l;
#pragma unroll
    for (int kk = 0; kk < 4; ++kk) bfr[kk] = bptr[kk * 64];
#pragma unroll
    for (int m = 0; m < 4; ++m) {
      f32x4 wacc = {b, b, b, b};  // bias folded into accumulator init
#pragma unroll
      for (int kk = 0; kk < 4; ++kk)
        wacc = __builtin_amdgcn_mfma_f32_16x16x32_bf16(afrag[m][kk], bfr[kk], wacc, 0, 0, 0);
      const f32x4 xs = *reinterpret_cast<const f32x4*>(&s_x[i][m * 16 + g * 4]);
#pragma unroll
      for (int r = 0; r < 4; ++r)
        msg[m][r] += fmaxf(wacc[r], 0.f) * xs[r];
    }
  }

#pragma unroll
  for (int m = 0; m < 4; ++m)
#pragma unroll
    for (int r = 0; r < 4; ++r)
      atomicAdd(&aggr[(size_t)s_dst[m * 16 + g * 4 + r] * CO + ocol], msg[m][r]);
}

extern "C" void kernel_launch(void* const* d_in, const int* in_sizes, int n_in,
                              void* d_out, int out_size, void* d_ws, size_t ws_size,
                              hipStream_t stream) {
  const float* x       = (const float*)d_in[0];
  const int*   ei      = (const int*)d_in[1];
  const float* eattr   = (const float*)d_in[2];
  const float* l1_ew1  = (const float*)d_in[3];
  const float* l1_eb1  = (const float*)d_in[4];
  const float* l1_ew2  = (const float*)d_in[5];
  const float* l1_eb2  = (const float*)d_in[6];
  const float* l1_root = (const float*)d_in[7];
  const float* l1_bias = (const float*)d_in[8];
  const float* l2_ew1  = (const float*)d_in[9];
  const float* l2_eb1  = (const float*)d_in[10];
  const float* l2_ew2  = (const float*)d_in[11];
  const float* l2_eb2  = (const float*)d_in[12];
  const float* l2_root = (const float*)d_in[13];
  const float* l2_bias = (const float*)d_in[14];

  const int* src = ei;
  const int* dst = ei + NE;

  float* P1 = (float*)d_ws;                       // [N,64] pre-relu layer-1 out
  float* Hb = P1 + NN * 64;                       // [N,64] relu'd node features
  unsigned short* B1 = (unsigned short*)(Hb + NN * 64);  // 2048*128 bf16 frag
  unsigned short* B2 = B1 + 2048 * 128;
  float* outf = (float*)d_out;

  k_reorder<<<128, 256, 0, stream>>>(l1_ew2, B1);
  k_reorder<<<128, 256, 0, stream>>>(l2_ew2, B2);
  k_root<32, 64><<<(NN * 64 + 255) / 256, 256, 0, stream>>>(x, l1_root, l1_bias, P1);
  k_edge<32, 64><<<NE / 64, 256, 0, stream>>>(src, dst, eattr, l1_ew1, l1_eb1, B1, l1_eb2, x, P1);
  k_relu<<<(NN * 64 + 255) / 256, 256, 0, stream>>>(P1, Hb, NN * 64);
  k_root<64, 32><<<(NN * 32 + 255) / 256, 256, 0, stream>>>(Hb, l2_root, l2_bias, outf);
  k_edge<64, 32><<<NE / 64, 256, 0, stream>>>(src, dst, eattr, l2_ew1, l2_eb1, B2, l2_eb2, Hb, outf);
}

// Round 2
// 108.442 us; speedup vs baseline: 1.0199x; 1.0199x over previous
//
#include <hip/hip_runtime.h>

#define NN 10000
#define NE 40000

typedef __attribute__((ext_vector_type(8))) short bf16x8;
typedef __attribute__((ext_vector_type(4))) float f32x4;
typedef __attribute__((ext_vector_type(8))) unsigned short u16x8;

__device__ inline unsigned short bf16rne(float f) {
  union { float f; unsigned u; } v; v.f = f;
  return (unsigned short)((v.u + 0x7FFFu + ((v.u >> 16) & 1u)) >> 16);
}

// ew2 [128 x 2048] f32 -> bf16 MFMA-B fragment order.
// element j of lane l, col-tile ct, k-chunk kk = B[kk*32+(l>>4)*8+j][ct*16+(l&15)]
// at ushort index ((ct*4+kk)*64+l)*8+j.
__global__ void k_reorder(const float* __restrict__ ew2, unsigned short* __restrict__ out) {
  const int l  = threadIdx.x & 63;
  const int kk = threadIdx.x >> 6;
  const int ct = blockIdx.x;
  const int col = ct * 16 + (l & 15);
  const int g = l >> 4;
  u16x8 v;
#pragma unroll
  for (int j = 0; j < 8; ++j) v[j] = bf16rne(ew2[(kk * 32 + g * 8 + j) * 2048 + col]);
  *reinterpret_cast<u16x8*>(out + ((size_t)((ct * 4 + kk) * 64 + l) * 8)) = v;
}

// ew1 [16 x 128] f32 -> bf16 B-frag, K padded to 32 with zeros. 8 col-tiles.
__global__ void k_reorder_e(const float* __restrict__ ew1, unsigned short* __restrict__ out) {
  const int l  = threadIdx.x & 63;
  const int ct = threadIdx.x >> 6;  // 512 threads -> 8 tiles
  const int g = l >> 4;
  u16x8 v;
#pragma unroll
  for (int j = 0; j < 8; ++j) {
    int k = g * 8 + j;
    v[j] = (k < 16) ? bf16rne(ew1[k * 128 + ct * 16 + (l & 15)]) : (unsigned short)0;
  }
  *reinterpret_cast<u16x8*>(out + ((size_t)(ct * 64 + l) * 8)) = v;
}

// out[n,KO] = (relu?)(xin[n,KI]) @ root[KI,KO] + bias[KO]
template <int KI, int KO, bool RELU_IN>
__global__ void k_root(const float* __restrict__ xin, const float* __restrict__ root,
                       const float* __restrict__ bias, float* __restrict__ out) {
  int idx = blockIdx.x * 256 + threadIdx.x;
  if (idx >= NN * KO) return;
  int n = idx / KO, o = idx % KO;
  float acc = bias[o];
#pragma unroll
  for (int k = 0; k < KI; ++k) {
    float v = xin[n * KI + k];
    if (RELU_IN) v = fmaxf(v, 0.f);
    acc += v * root[k * KO + o];
  }
  out[idx] = acc;
}

// Fused per-edge kernel, 64 edges/block, 4 waves, column-half split (grid x2).
// H = relu(eattr@ew1+eb1) via MFMA; W = relu(H@ew2+eb2) fused with per-edge
// x[src] contraction; partial-i sums combined in LDS; one atomicAdd per (e,ocol).
template <int CI, int CO, bool RELU_IN>
__global__ __launch_bounds__(256, 4) void k_edge(
    const int* __restrict__ src, const int* __restrict__ dst,
    const float* __restrict__ eattr,
    const unsigned short* __restrict__ ew1f, const float* __restrict__ eb1,
    const unsigned short* __restrict__ bfrag, const float* __restrict__ eb2,
    const float* __restrict__ xin, float* __restrict__ aggr) {
  constexpr int TE = 64;
  constexpr int XS = 68;
  const int tid = threadIdx.x;
  const int eb = blockIdx.x >> 1, hf = blockIdx.x & 1;
  const int e0 = eb * TE;

  __shared__ int s_src[TE];
  __shared__ int s_dst[TE];
  __shared__ float s_x[CI][XS];
  __shared__ unsigned short s_hfrag[16 * 64 * 8];  // 16 KB; reused as combine buf

  if (tid < TE) { s_src[tid] = src[e0 + tid]; s_dst[tid] = dst[e0 + tid]; }
  __syncthreads();

  // gather x[src] -> transposed LDS
  for (int i = tid; i < TE * CI; i += 256) {
    int e = i / CI, c = i % CI;
    float v = xin[(size_t)s_src[e] * CI + c];
    if (RELU_IN) v = fmaxf(v, 0.f);
    s_x[c][e] = v;
  }

  const int l = tid & 63;
  const int w = tid >> 6;
  const int g = l >> 4;
  const int c16 = l & 15;

  // ---- H via MFMA: wave w computes edge-tile m=w (16 edges), all 128 channels
  {
    bf16x8 ea;
#pragma unroll
    for (int j = 0; j < 8; ++j) ea[j] = 0;
    if (g < 2) {
      const float* p = eattr + (size_t)(e0 + 16 * w + c16) * 16 + g * 8;
      f32x4 v0 = *reinterpret_cast<const f32x4*>(p);
      f32x4 v1 = *reinterpret_cast<const f32x4*>(p + 4);
#pragma unroll
      for (int j = 0; j < 4; ++j) { ea[j] = bf16rne(v0[j]); ea[4 + j] = bf16rne(v1[j]); }
    }
#pragma unroll
    for (int ct = 0; ct < 8; ++ct) {
      bf16x8 bw = *reinterpret_cast<const bf16x8*>(ew1f + ((size_t)(ct * 64 + l) * 8));
      float bb = eb1[ct * 16 + c16];
      f32x4 acc = {bb, bb, bb, bb};
      acc = __builtin_amdgcn_mfma_f32_16x16x32_bf16(ea, bw, acc, 0, 0, 0);
#pragma unroll
      for (int r = 0; r < 4; ++r) {
        int eloc = g * 4 + r;                 // row within tile
        int c = ct * 16 + c16;                // channel 0..127
        s_hfrag[(((w * 4) + (c >> 5)) * 64 + ((c >> 3) & 3) * 16 + eloc) * 8 + (c & 7)] =
            bf16rne(fmaxf(acc[r], 0.f));
      }
    }
  }
  __syncthreads();

  // A fragments for the big GEMM (linear conflict-free b128 reads)
  bf16x8 afrag[4][4];
#pragma unroll
  for (int m = 0; m < 4; ++m)
#pragma unroll
    for (int kk = 0; kk < 4; ++kk)
      afrag[m][kk] = *reinterpret_cast<const bf16x8*>(&s_hfrag[((m * 4 + kk) * 64 + l) * 8]);
  __syncthreads();  // protect s_hfrag before reuse as combine buffer

  float msg[4][4];
#pragma unroll
  for (int m = 0; m < 4; ++m)
#pragma unroll
    for (int r = 0; r < 4; ++r) msg[m][r] = 0.f;

  int ot = 0, ip = 0, ocol;
  if (CI == 32) { ot = hf * 2 + (w & 1); ip = w >> 1; ocol = ot * 16 + c16; }
  else { ocol = hf * 16 + c16; }

  for (int t = 0; t < 16; ++t) {
    int i, ct;
    if (CI == 32) { i = ip + 2 * t; ct = i * 4 + ot; }
    else          { i = w + 4 * t;  ct = i * 2 + hf; }
    const bf16x8* bptr = reinterpret_cast<const bf16x8*>(bfrag) + (size_t)ct * 4 * 64 + l;
    bf16x8 bfr[4];
#pragma unroll
    for (int kk = 0; kk < 4; ++kk) bfr[kk] = bptr[kk * 64];
    const float b = eb2[i * CO + ocol];
#pragma unroll
    for (int m = 0; m < 4; ++m) {
      f32x4 wacc = {b, b, b, b};
#pragma unroll
      for (int kk = 0; kk < 4; ++kk)
        wacc = __builtin_amdgcn_mfma_f32_16x16x32_bf16(afrag[m][kk], bfr[kk], wacc, 0, 0, 0);
      const f32x4 xs = *reinterpret_cast<const f32x4*>(&s_x[i][m * 16 + g * 4]);
#pragma unroll
      for (int r = 0; r < 4; ++r)
        msg[m][r] += fmaxf(wacc[r], 0.f) * xs[r];
    }
  }

  // ---- combine partial-i sums in LDS (reuse s_hfrag), then single atomic
  float* cb = reinterpret_cast<float*>(s_hfrag);
  if (CI == 32) {
    if (w >= 2) {
#pragma unroll
      for (int m = 0; m < 4; ++m)
#pragma unroll
        for (int r = 0; r < 4; ++r)
          cb[((w - 2) * 64 + m * 16 + g * 4 + r) * 17 + c16] = msg[m][r];
    }
  } else {
    if (w >= 1) {
#pragma unroll
      for (int m = 0; m < 4; ++m)
#pragma unroll
        for (int r = 0; r < 4; ++r)
          cb[((w - 1) * 64 + m * 16 + g * 4 + r) * 17 + c16] = msg[m][r];
    }
  }
  __syncthreads();

  const bool owner = (CI == 32) ? (w < 2) : (w == 0);
  if (owner) {
    if (CI == 32) {
#pragma unroll
      for (int m = 0; m < 4; ++m)
#pragma unroll
        for (int r = 0; r < 4; ++r)
          msg[m][r] += cb[(w * 64 + m * 16 + g * 4 + r) * 17 + c16];
    } else {
#pragma unroll
      for (int s = 0; s < 3; ++s)
#pragma unroll
        for (int m = 0; m < 4; ++m)
#pragma unroll
          for (int r = 0; r < 4; ++r)
            msg[m][r] += cb[(s * 64 + m * 16 + g * 4 + r) * 17 + c16];
    }
#pragma unroll
    for (int m = 0; m < 4; ++m)
#pragma unroll
      for (int r = 0; r < 4; ++r)
        atomicAdd(&aggr[(size_t)s_dst[m * 16 + g * 4 + r] * CO + ocol], msg[m][r]);
  }
}

extern "C" void kernel_launch(void* const* d_in, const int* in_sizes, int n_in,
                              void* d_out, int out_size, void* d_ws, size_t ws_size,
                              hipStream_t stream) {
  const float* x       = (const float*)d_in[0];
  const int*   ei      = (const int*)d_in[1];
  const float* eattr   = (const float*)d_in[2];
  const float* l1_ew1  = (const float*)d_in[3];
  const float* l1_eb1  = (const float*)d_in[4];
  const float* l1_ew2  = (const float*)d_in[5];
  const float* l1_eb2  = (const float*)d_in[6];
  const float* l1_root = (const float*)d_in[7];
  const float* l1_bias = (const float*)d_in[8];
  const float* l2_ew1  = (const float*)d_in[9];
  const float* l2_eb1  = (const float*)d_in[10];
  const float* l2_ew2  = (const float*)d_in[11];
  const float* l2_eb2  = (const float*)d_in[12];
  const float* l2_root = (const float*)d_in[13];
  const float* l2_bias = (const float*)d_in[14];

  const int* src = ei;
  const int* dst = ei + NE;

  float* P1 = (float*)d_ws;                                // [N,64] pre-relu L1 out
  unsigned short* B1  = (unsigned short*)(P1 + NN * 64);   // 2048*128 bf16 ew2 frag
  unsigned short* B2  = B1 + 2048 * 128;
  unsigned short* B1e = B2 + 2048 * 128;                   // 8*64*8 bf16 ew1 frag
  unsigned short* B2e = B1e + 8 * 64 * 8;
  float* outf = (float*)d_out;

  k_reorder<<<128, 256, 0, stream>>>(l1_ew2, B1);
  k_reorder<<<128, 256, 0, stream>>>(l2_ew2, B2);
  k_reorder_e<<<1, 512, 0, stream>>>(l1_ew1, B1e);
  k_reorder_e<<<1, 512, 0, stream>>>(l2_ew1, B2e);

  k_root<32, 64, false><<<(NN * 64 + 255) / 256, 256, 0, stream>>>(x, l1_root, l1_bias, P1);
  k_edge<32, 64, false><<<2 * NE / 64, 256, 0, stream>>>(src, dst, eattr, B1e, l1_eb1, B1, l1_eb2, x, P1);
  k_root<64, 32, true><<<(NN * 32 + 255) / 256, 256, 0, stream>>>(P1, l2_root, l2_bias, outf);
  k_edge<64, 32, true><<<2 * NE / 64, 256, 0, stream>>>(src, dst, eattr, B2e, l2_eb1, B2, l2_eb2, P1, outf);
}